// Round 6
// baseline (389.493 us; speedup 1.0000x reference)
//
#include <hip/hip_runtime.h>
#include <math.h>

#define BB 4096
#define SEQ 50
#define KK 4
#define HH 64
#define NCOL (KK*SEQ)      // 200
#define NPART 64           // partial-sum groups over batch
#define BPP (BB/NPART)     // 64 batches per group

__device__ __forceinline__ float readlane_f32(float v, int lane) {
    return __int_as_float(__builtin_amdgcn_readlane(__float_as_int(v), lane));
}

// ---------------------------------------------------------------------------
// INIT: partial softmax denominators for iteration 0 (unshifted exp: |cw|
// stays < ~30 across iterations, exp fits fp32 comfortably) + zero the
// iter-1/2 partial accumulators.  [verbatim from the round-0 verified kernel]
// ---------------------------------------------------------------------------
__global__ void init_kernel(const float* __restrict__ cw,
                            float* __restrict__ part0,
                            float* __restrict__ part1,
                            float* __restrict__ part2) {
    const int p = blockIdx.x;
    const int t = threadIdx.x;
    if (t < NCOL) {
        const float* row = cw + (size_t)p * BPP * NCOL + t;
        float s = 0.f;
#pragma unroll 8
        for (int b = 0; b < BPP; b++) s += __expf(row[b * NCOL]);
        part0[p * NCOL + t] = s;
        part1[p * NCOL + t] = 0.f;
        part2[p * NCOL + t] = 0.f;
    }
}

// ---------------------------------------------------------------------------
// UPDATE: one routing iteration. grid = BB x 256; wave = k, lane = h.
// Delta phase: lane s re-reads row x[b,s,k,0:64] (16x float4, L2-hot) and
// dots it with v broadcast via readlane.
//
// CORRECTNESS-CRITICAL: the delta block runs under FULL exec (lanes >= SEQ
// compute a throwaway delta on a clamped row). If it were guarded by
// if(h<SEQ), the compiler may sink v's computation into the branch, leaving
// lanes 50-63's v register unwritten -- readlane(v, 50..63) then reads
// garbage (the r1/r2/r5 failure mechanism). Only the store is predicated.
// ---------------------------------------------------------------------------
template <int ITER>   // 0,1 = routing update; 2 = final (writes out)
__global__ __launch_bounds__(256, 8)
void update_kernel(const float* __restrict__ cw_src,
                   float* __restrict__ cw_dst,
                   const float* __restrict__ x,
                   const int* __restrict__ mask,
                   const float* __restrict__ part_in,
                   float* __restrict__ part_out,
                   float* __restrict__ out) {
    const int b = blockIdx.x;
    const int k = threadIdx.x >> 6;
    const int h = threadIdx.x & 63;

    __shared__ float scol[NCOL];

    // column denominators: thread t < NCOL sums NPART partials (L2-hot)
    if (threadIdx.x < NCOL) {
        float s = 0.f;
#pragma unroll 16
        for (int p = 0; p < NPART; p++) s += part_in[p * NCOL + threadIdx.x];
        scol[threadIdx.x] = s;
    }
    __syncthreads();

    // lane s < SEQ: w_s = mask ? exp(c)/colsum : 0
    float wlane = 0.f, c = 0.f;
    if (h < SEQ) {
        c = cw_src[(size_t)b * NCOL + k * SEQ + h];
        float e = __expf(c) / scol[k * SEQ + h];
        wlane = (mask[b * SEQ + h] != 0) ? e : 0.f;
    }

    // v_h = sum_s w_s * x[b,s,k,h] ; w_s broadcast via readlane (sources are
    // lanes 0..49 only, and this loop runs under full exec).
    const float* xp = x + (size_t)b * (SEQ * KK * HH) + k * HH + h;
    float v = 0.f;
#pragma unroll
    for (int s = 0; s < SEQ; s++)
        v = fmaf(readlane_f32(wlane, s), xp[s * (KK * HH)], v);

    // squash: n2 = ||v||^2 (6 shfls)
    float n2 = v * v;
#pragma unroll
    for (int off = 32; off >= 1; off >>= 1) n2 += __shfl_xor(n2, off, 64);
    const float scalar = n2 / ((1.f + n2) * sqrtf(n2 + 1e-9f));
    v *= scalar;

    // Pin v into its VGPR at full exec: opaque read-modify-write stops the
    // compiler from sinking v's computation into any divergent region below.
    asm volatile("" : "+v"(v));

    if (ITER == 2) {
        out[(size_t)b * (KK * HH) + k * HH + h] = v;
    } else {
        // delta_s = x[b,s,k,:] . v  -- FULL EXEC (see header comment).
        const int hs = (h < SEQ) ? h : (SEQ - 1);   // clamped throwaway row
        const float4* xs = (const float4*)(x + (size_t)b * (SEQ * KK * HH)
                                           + (size_t)hs * (KK * HH) + k * HH);
        float d0 = 0.f, d1 = 0.f, d2 = 0.f, d3 = 0.f;
#pragma unroll 4
        for (int j = 0; j < HH / 4; j++) {
            float4 xv = xs[j];
            d0 = fmaf(xv.x, readlane_f32(v, 4 * j + 0), d0);
            d1 = fmaf(xv.y, readlane_f32(v, 4 * j + 1), d1);
            d2 = fmaf(xv.z, readlane_f32(v, 4 * j + 2), d2);
            d3 = fmaf(xv.w, readlane_f32(v, 4 * j + 3), d3);
        }
        if (h < SEQ) {
            const float nc = c + ((d0 + d1) + (d2 + d3));
            cw_dst[(size_t)b * NCOL + k * SEQ + h] = nc;
            atomicAdd(&part_out[(b >> 6) * NCOL + k * SEQ + h], __expf(nc));
        }
    }
}

extern "C" void kernel_launch(void* const* d_in, const int* in_sizes, int n_in,
                              void* d_out, int out_size, void* d_ws, size_t ws_size,
                              hipStream_t stream) {
    const int*   mask  = (const int*)d_in[0];
    const float* x     = (const float*)d_in[1];
    const float* cw_in = (const float*)d_in[2];
    float* out = (float*)d_out;

    float* cw_ws = (float*)d_ws;                       // BB*NCOL floats
    float* part0 = cw_ws + (size_t)BB * NCOL;          // NPART*NCOL
    float* part1 = part0 + NPART * NCOL;
    float* part2 = part1 + NPART * NCOL;

    init_kernel<<<NPART, 256, 0, stream>>>(cw_in, part0, part1, part2);
    update_kernel<0><<<BB, 256, 0, stream>>>(cw_in, cw_ws, x, mask, part0, part1, nullptr);
    update_kernel<1><<<BB, 256, 0, stream>>>(cw_ws, cw_ws, x, mask, part1, part2, nullptr);
    update_kernel<2><<<BB, 256, 0, stream>>>(cw_ws, nullptr, x, mask, part2, nullptr, out);
}